// Round 2
// baseline (2411.494 us; speedup 1.0000x reference)
//
#include <hip/hip_runtime.h>
#include <stdint.h>

#define B_DIM 8
#define S_DIM 4096
#define F_DIM 512
#define H_DIM 2048
#define W_DIM 16
#define L_DIM 4081               // S - W + 1
#define M_TOT 32648              // B * L
#define K1_DIM 8192              // W * F
#define SXF 2097152              // S * F

typedef __bf16 bf16x8 __attribute__((ext_vector_type(8)));
typedef float f32x4 __attribute__((ext_vector_type(4)));

__device__ __forceinline__ unsigned short f2bf(float f) {
  union { float f; uint32_t u; } a; a.f = f;
  return (unsigned short)((a.u + 0x7fffu + ((a.u >> 16) & 1u)) >> 16);
}

__device__ __forceinline__ void async16(const void* g, void* l) {
  __builtin_amdgcn_global_load_lds(
      (__attribute__((address_space(1))) void*)(uintptr_t)g,
      (__attribute__((address_space(3))) void*)l, 16, 0, 0);
}

// ---------------- GEMM1: h = relu(x_hankel @ w1 + b1), bf16 in, bf16 out ----
// Double-buffered LDS, ONE barrier per K-iteration: prefetch of tile kt+1 is
// issued right after the barrier, overlapping ds_read+MFMA of tile kt; the
// vmcnt(0) drain for it happens only at the next barrier.
__global__ __launch_bounds__(256) void gemm1_kernel(
    const unsigned short* __restrict__ xb,
    const unsigned short* __restrict__ w1t,
    const float* __restrict__ bias1,
    unsigned short* __restrict__ h)
{
  __shared__ alignas(16) unsigned short lsA[8192];   // 2 x 8 KB
  __shared__ alignas(16) unsigned short lsB[8192];   // 2 x 8 KB

  const int tid  = threadIdx.x;
  const int lane = tid & 63;
  const int wave = tid >> 6;
  const int mt = blockIdx.x;
  const int nt = blockIdx.y;

  // staging decode: chunk c0 = tid (m=c&15, g=(c>>4)&3, t=c>>6); c1 = tid+256
  const int sm = tid & 15;
  const int sg = (tid >> 4) & 3;
  const int st = tid >> 6;

  int row0 = mt * 128 + st * 16 + sm;
  int row1 = row0 + 64;
  if (row0 >= M_TOT) row0 = M_TOT - 1;
  if (row1 >= M_TOT) row1 = M_TOT - 1;
  const int b0 = row0 / L_DIM, l0 = row0 - b0 * L_DIM;
  const int b1r = row1 / L_DIM, l1 = row1 - b1r * L_DIM;
  const unsigned short* pA0 = xb + (size_t)b0  * SXF + (size_t)l0 * F_DIM + sg * 8;
  const unsigned short* pA1 = xb + (size_t)b1r * SXF + (size_t)l1 * F_DIM + sg * 8;

  const int col0 = nt * 128 + st * 16 + sm;
  const unsigned short* pB0 = w1t + (size_t)col0 * K1_DIM + sg * 8;
  const unsigned short* pB1 = pB0 + (size_t)64 * K1_DIM;

  const int wm = wave >> 1, wn = wave & 1;

  f32x4 acc[4][4] = {};

  // prologue: stage tile 0 into buffer 0
  {
    unsigned short* a = lsA + wave * 512;
    unsigned short* b = lsB + wave * 512;
    async16(pA0, a); async16(pA1, a + 2048);
    async16(pB0, b); async16(pB1, b + 2048);
    pA0 += 32; pA1 += 32; pB0 += 32; pB1 += 32;
  }

  int cbuf = 0;
  const int KT = K1_DIM / 32;
  for (int kt = 0; kt < KT; ++kt) {
    __syncthreads();                       // tile kt ready in buf cbuf
    if (kt + 1 < KT) {                     // prefetch kt+1 into other buffer
      unsigned short* a = lsA + (cbuf ^ 1) * 4096 + wave * 512;
      unsigned short* b = lsB + (cbuf ^ 1) * 4096 + wave * 512;
      async16(pA0, a); async16(pA1, a + 2048);
      async16(pB0, b); async16(pB1, b + 2048);
      pA0 += 32; pA1 += 32; pB0 += 32; pB1 += 32;
    }
    const bf16x8* lA = (const bf16x8*)(lsA + cbuf * 4096) + wm * 256 + lane;
    const bf16x8* lB = (const bf16x8*)(lsB + cbuf * 4096) + wn * 256 + lane;
    bf16x8 af[4], bfr[4];
#pragma unroll
    for (int t = 0; t < 4; ++t) af[t] = lA[t * 64];
#pragma unroll
    for (int u = 0; u < 4; ++u) bfr[u] = lB[u * 64];
#pragma unroll
    for (int t = 0; t < 4; ++t)
#pragma unroll
      for (int u = 0; u < 4; ++u)
        acc[t][u] = __builtin_amdgcn_mfma_f32_16x16x32_bf16(af[t], bfr[u], acc[t][u], 0, 0, 0);
    cbuf ^= 1;
  }

  // C/D layout: col = lane&15, row = (lane>>4)*4 + reg
  const int ncol = nt * 128 + wn * 64 + (lane & 15);
  const int mrow = mt * 128 + wm * 64 + (lane >> 4) * 4;
#pragma unroll
  for (int u = 0; u < 4; ++u) {
    const int n = ncol + u * 16;
    const float bv = bias1[n];
#pragma unroll
    for (int t = 0; t < 4; ++t) {
#pragma unroll
      for (int r = 0; r < 4; ++r) {
        const int m = mrow + t * 16 + r;
        if (m < M_TOT) {
          float v = acc[t][u][r] + bv;
          v = v > 0.f ? v : 0.f;
          h[(size_t)m * H_DIM + n] = f2bf(v);
        }
      }
    }
  }
}

// ---------------- GEMM2: y = h @ w2 + b2, fp32 out with Hankel-pad store ----
__global__ __launch_bounds__(256) void gemm2_kernel(
    const unsigned short* __restrict__ hmat,
    const unsigned short* __restrict__ w2t,   // [512][2048]
    const float* __restrict__ bias2,
    float* __restrict__ out)
{
  __shared__ alignas(16) unsigned short lsA[8192];
  __shared__ alignas(16) unsigned short lsB[8192];

  const int tid  = threadIdx.x;
  const int lane = tid & 63;
  const int wave = tid >> 6;
  const int mt = blockIdx.x;
  const int nt = blockIdx.y;

  const int sm = tid & 15;
  const int sg = (tid >> 4) & 3;
  const int st = tid >> 6;

  int row0 = mt * 128 + st * 16 + sm;
  int row1 = row0 + 64;
  if (row0 >= M_TOT) row0 = M_TOT - 1;
  if (row1 >= M_TOT) row1 = M_TOT - 1;
  const unsigned short* pA0 = hmat + (size_t)row0 * H_DIM + sg * 8;
  const unsigned short* pA1 = hmat + (size_t)row1 * H_DIM + sg * 8;

  const int col0 = nt * 128 + st * 16 + sm;
  const unsigned short* pB0 = w2t + (size_t)col0 * H_DIM + sg * 8;
  const unsigned short* pB1 = pB0 + (size_t)64 * H_DIM;

  const int wm = wave >> 1, wn = wave & 1;

  f32x4 acc[4][4] = {};

  {
    unsigned short* a = lsA + wave * 512;
    unsigned short* b = lsB + wave * 512;
    async16(pA0, a); async16(pA1, a + 2048);
    async16(pB0, b); async16(pB1, b + 2048);
    pA0 += 32; pA1 += 32; pB0 += 32; pB1 += 32;
  }

  int cbuf = 0;
  const int KT = H_DIM / 32;
  for (int kt = 0; kt < KT; ++kt) {
    __syncthreads();
    if (kt + 1 < KT) {
      unsigned short* a = lsA + (cbuf ^ 1) * 4096 + wave * 512;
      unsigned short* b = lsB + (cbuf ^ 1) * 4096 + wave * 512;
      async16(pA0, a); async16(pA1, a + 2048);
      async16(pB0, b); async16(pB1, b + 2048);
      pA0 += 32; pA1 += 32; pB0 += 32; pB1 += 32;
    }
    const bf16x8* lA = (const bf16x8*)(lsA + cbuf * 4096) + wm * 256 + lane;
    const bf16x8* lB = (const bf16x8*)(lsB + cbuf * 4096) + wn * 256 + lane;
    bf16x8 af[4], bfr[4];
#pragma unroll
    for (int t = 0; t < 4; ++t) af[t] = lA[t * 64];
#pragma unroll
    for (int u = 0; u < 4; ++u) bfr[u] = lB[u * 64];
#pragma unroll
    for (int t = 0; t < 4; ++t)
#pragma unroll
      for (int u = 0; u < 4; ++u)
        acc[t][u] = __builtin_amdgcn_mfma_f32_16x16x32_bf16(af[t], bfr[u], acc[t][u], 0, 0, 0);
    cbuf ^= 1;
  }

  const int ncol = nt * 128 + wn * 64 + (lane & 15);
  const int mrow = mt * 128 + wm * 64 + (lane >> 4) * 4;
#pragma unroll
  for (int u = 0; u < 4; ++u) {
    const int n = ncol + u * 16;
    const float bv = bias2[n];
#pragma unroll
    for (int t = 0; t < 4; ++t) {
#pragma unroll
      for (int r = 0; r < 4; ++r) {
        const int m = mrow + t * 16 + r;
        if (m < M_TOT) {
          const int b = m / L_DIM;
          const int l = m - b * L_DIM;
          out[(size_t)b * SXF + (size_t)l * F_DIM + n] = acc[t][u][r] + bv;
        }
      }
    }
  }
}

// ---------------- conversion / transpose / pad helpers ----------------------
__global__ void cvt_bf16_kernel(const float* __restrict__ in,
                                unsigned short* __restrict__ out, int n4) {
  int idx = blockIdx.x * 256 + threadIdx.x;
  if (idx < n4) {
    float4 v = ((const float4*)in)[idx];
    ushort4 o;
    o.x = f2bf(v.x); o.y = f2bf(v.y); o.z = f2bf(v.z); o.w = f2bf(v.w);
    ((ushort4*)out)[idx] = o;
  }
}

// out[c][r] = bf16(in[r][c]); R, C multiples of 64
__global__ void transpose_cvt_kernel(const float* __restrict__ in,
                                     unsigned short* __restrict__ out, int R, int C) {
  __shared__ unsigned short tile[64][72];
  const int tx = threadIdx.x & 15;
  const int ty = threadIdx.x >> 4;
  const int r0 = blockIdx.x * 64;
  const int c0 = blockIdx.y * 64;
#pragma unroll
  for (int i = 0; i < 4; ++i) {
    const int r = r0 + ty + i * 16;
    float4 v = *(const float4*)(in + (size_t)r * C + c0 + tx * 4);
    tile[ty + i * 16][tx * 4 + 0] = f2bf(v.x);
    tile[ty + i * 16][tx * 4 + 1] = f2bf(v.y);
    tile[ty + i * 16][tx * 4 + 2] = f2bf(v.z);
    tile[ty + i * 16][tx * 4 + 3] = f2bf(v.w);
  }
  __syncthreads();
#pragma unroll
  for (int i = 0; i < 4; ++i) {
    const int c = c0 + ty + i * 16;
    ushort4 o;
    o.x = tile[tx * 4 + 0][ty + i * 16];
    o.y = tile[tx * 4 + 1][ty + i * 16];
    o.z = tile[tx * 4 + 2][ty + i * 16];
    o.w = tile[tx * 4 + 3][ty + i * 16];
    *(ushort4*)(out + (size_t)c * R + r0 + tx * 4) = o;
  }
}

__global__ void zero_pad_kernel(float* __restrict__ out) {
  int idx = blockIdx.x * 256 + threadIdx.x;          // 8 * 15 * 128 float4s
  if (idx < B_DIM * 15 * 128) {
    int b = idx / (15 * 128);
    int rem = idx - b * (15 * 128);
    int l = L_DIM + rem / 128;
    int f4 = rem - (rem / 128) * 128;
    ((float4*)out)[(size_t)b * (SXF / 4) + (size_t)l * 128 + f4] =
        make_float4(0.f, 0.f, 0.f, 0.f);
  }
}

__global__ void fill_sentinel(float* out, int n) {   // distinctive ws-too-small marker
  int idx = blockIdx.x * 256 + threadIdx.x;
  if (idx < n) out[idx] = 12345.0f;
}

extern "C" void kernel_launch(void* const* d_in, const int* in_sizes, int n_in,
                              void* d_out, int out_size, void* d_ws, size_t ws_size,
                              hipStream_t stream) {
  const float* x  = (const float*)d_in[0];
  const float* w1 = (const float*)d_in[1];
  const float* b1 = (const float*)d_in[2];
  const float* w2 = (const float*)d_in[3];
  const float* b2 = (const float*)d_in[4];
  float* out = (float*)d_out;

  const size_t OFF_H   = 0;                               // 32648*2048*2 = 133726208
  const size_t OFF_XB  = 133726208;                       // 16777216*2   = 33554432
  const size_t OFF_W1T = OFF_XB + 33554432;               // 8192*2048*2  = 33554432
  const size_t OFF_W2T = OFF_W1T + 33554432;              // 2048*512*2   = 2097152
  const size_t WS_NEED = OFF_W2T + 2097152;               // ~202.9 MB

  if (ws_size < WS_NEED) {
    fill_sentinel<<<65536, 256, 0, stream>>>(out, out_size);
    return;
  }

  unsigned short* hbuf = (unsigned short*)((char*)d_ws + OFF_H);
  unsigned short* xb   = (unsigned short*)((char*)d_ws + OFF_XB);
  unsigned short* w1t  = (unsigned short*)((char*)d_ws + OFF_W1T);
  unsigned short* w2t  = (unsigned short*)((char*)d_ws + OFF_W2T);

  cvt_bf16_kernel<<<16384, 256, 0, stream>>>(x, xb, 4194304);
  transpose_cvt_kernel<<<dim3(128, 32), 256, 0, stream>>>(w1, w1t, 8192, 2048);
  transpose_cvt_kernel<<<dim3(32, 8), 256, 0, stream>>>(w2, w2t, 2048, 512);
  gemm1_kernel<<<dim3(256, 16), 256, 0, stream>>>(xb, w1t, b1, hbuf);
  gemm2_kernel<<<dim3(256, 4), 256, 0, stream>>>(hbuf, w2t, b2, out);
  zero_pad_kernel<<<60, 256, 0, stream>>>(out);
}

// Round 3
// 2002.969 us; speedup vs baseline: 1.2040x; 1.2040x over previous
//
#include <hip/hip_runtime.h>
#include <stdint.h>

#define B_DIM 8
#define S_DIM 4096
#define F_DIM 512
#define H_DIM 2048
#define W_DIM 16
#define L_DIM 4081               // S - W + 1
#define M_TOT 32648              // B * L
#define K1_DIM 8192              // W * F
#define SXF 2097152              // S * F

typedef __bf16 bf16x8 __attribute__((ext_vector_type(8)));
typedef float f32x4 __attribute__((ext_vector_type(4)));

__device__ __forceinline__ unsigned short f2bf(float f) {
  union { float f; uint32_t u; } a; a.f = f;
  return (unsigned short)((a.u + 0x7fffu + ((a.u >> 16) & 1u)) >> 16);
}

__device__ __forceinline__ void async16(const void* g, void* l) {
  __builtin_amdgcn_global_load_lds(
      (__attribute__((address_space(1))) void*)(uintptr_t)g,
      (__attribute__((address_space(3))) void*)l, 16, 0, 0);
}

// ---------------- GEMM1: h = relu(x_hankel @ w1 + b1) ----------------------
// 256x256 block tile, BK=32, 512 threads (8 waves), each wave 64x128.
// XCD swizzle: nt = blockIdx & 7 -> each XCD works one B-column (4 MB ~ L2),
// so B stages from L2 and only the A (Hankel) stream hits L3. Logical
// staging traffic halves vs 128^2 tiles: 17.2 -> 8.6 GB.
// LDS fragment-order layout: chunk c (16B) = row-block T (16 rows) * 64
// + kgroup g * 16 + m16; consumer lane reads chunk T*64+lane (ds_read_b128,
// conflict-free) and global_load_lds (uniform base + lane*16) stages it.
__global__ __launch_bounds__(512) void gemm1_kernel(
    const unsigned short* __restrict__ xb,
    const unsigned short* __restrict__ w1t,
    const float* __restrict__ bias1,
    unsigned short* __restrict__ h)
{
  __shared__ alignas(16) unsigned short lsA[16384];  // 2 stages x 16 KB
  __shared__ alignas(16) unsigned short lsB[16384];

  const int tid  = threadIdx.x;
  const int lane = tid & 63;
  const int wave = tid >> 6;           // 0..7
  const int id = blockIdx.x;
  const int nt = id & 7;               // XCD-pinned B column
  const int mt = id >> 3;

  // staging decode: chunk c0 = tid (m16=c&15, g=(c>>4)&3, T=c>>6), c1 = tid+512
  const int m16 = tid & 15;
  const int g   = (tid >> 4) & 3;
  const int T0  = tid >> 6;            // 0..7 ; c1 has T0+8

  int rowA0 = mt * 256 + T0 * 16 + m16;
  int rowA1 = rowA0 + 128;             // (T0+8)*16
  if (rowA0 >= M_TOT) rowA0 = M_TOT - 1;
  if (rowA1 >= M_TOT) rowA1 = M_TOT - 1;
  const int b0 = rowA0 / L_DIM, l0 = rowA0 - b0 * L_DIM;
  const int b1 = rowA1 / L_DIM, l1 = rowA1 - b1 * L_DIM;
  const unsigned short* pA0 = xb + (size_t)b0 * SXF + (size_t)l0 * F_DIM + g * 8;
  const unsigned short* pA1 = xb + (size_t)b1 * SXF + (size_t)l1 * F_DIM + g * 8;

  const int colB0 = nt * 256 + T0 * 16 + m16;
  const unsigned short* pB0 = w1t + (size_t)colB0 * K1_DIM + g * 8;
  const unsigned short* pB1 = pB0 + (size_t)128 * K1_DIM;

  const int wm = wave >> 1;            // 0..3 : 64-row band
  const int wn = wave & 1;             // 0..1 : 128-col band

  f32x4 acc[4][8] = {};

  // prologue: stage tile 0 into buffer 0 (chunk c -> offset c*16B)
  {
    unsigned short* a = lsA + tid * 8;
    unsigned short* b = lsB + tid * 8;
    async16(pA0, a); async16(pA1, a + 4096);
    async16(pB0, b); async16(pB1, b + 4096);
    pA0 += 32; pA1 += 32; pB0 += 32; pB1 += 32;
  }

  int cbuf = 0;
  const int KT = K1_DIM / 32;          // 256
  for (int kt = 0; kt < KT; ++kt) {
    __syncthreads();                   // tile kt ready in buf cbuf
    if (kt + 1 < KT) {                 // prefetch kt+1 into other buffer
      unsigned short* a = lsA + (cbuf ^ 1) * 8192 + tid * 8;
      unsigned short* b = lsB + (cbuf ^ 1) * 8192 + tid * 8;
      async16(pA0, a); async16(pA1, a + 4096);
      async16(pB0, b); async16(pB1, b + 4096);
      pA0 += 32; pA1 += 32; pB0 += 32; pB1 += 32;
    }
    const bf16x8* lA = (const bf16x8*)(lsA + cbuf * 8192) + wm * 256 + lane;
    const bf16x8* lB = (const bf16x8*)(lsB + cbuf * 8192) + wn * 512 + lane;
    bf16x8 af[4], bfr[8];
#pragma unroll
    for (int t = 0; t < 4; ++t) af[t] = lA[t * 64];
#pragma unroll
    for (int u = 0; u < 8; ++u) bfr[u] = lB[u * 64];
#pragma unroll
    for (int t = 0; t < 4; ++t)
#pragma unroll
      for (int u = 0; u < 8; ++u)
        acc[t][u] = __builtin_amdgcn_mfma_f32_16x16x32_bf16(af[t], bfr[u], acc[t][u], 0, 0, 0);
    cbuf ^= 1;
  }

  // C/D layout: col = lane&15, row = (lane>>4)*4 + reg
  const int ncol = nt * 256 + wn * 128 + (lane & 15);
  const int mrow = mt * 256 + wm * 64 + (lane >> 4) * 4;
#pragma unroll
  for (int u = 0; u < 8; ++u) {
    const int n = ncol + u * 16;
    const float bv = bias1[n];
#pragma unroll
    for (int t = 0; t < 4; ++t) {
#pragma unroll
      for (int r = 0; r < 4; ++r) {
        const int m = mrow + t * 16 + r;
        if (m < M_TOT) {
          float v = acc[t][u][r] + bv;
          v = v > 0.f ? v : 0.f;
          h[(size_t)m * H_DIM + n] = f2bf(v);
        }
      }
    }
  }
}

// ---------------- GEMM2: y = h @ w2 + b2, fp32 out with Hankel-pad store ----
__global__ __launch_bounds__(512) void gemm2_kernel(
    const unsigned short* __restrict__ hmat,
    const unsigned short* __restrict__ w2t,   // [512][2048]
    const float* __restrict__ bias2,
    float* __restrict__ out)
{
  __shared__ alignas(16) unsigned short lsA[16384];
  __shared__ alignas(16) unsigned short lsB[16384];

  const int tid  = threadIdx.x;
  const int lane = tid & 63;
  const int wave = tid >> 6;
  const int id = blockIdx.x;
  const int nt = id & 1;               // 2 col tiles of 256 (N=512)
  const int mt = id >> 1;

  const int m16 = tid & 15;
  const int g   = (tid >> 4) & 3;
  const int T0  = tid >> 6;

  int rowA0 = mt * 256 + T0 * 16 + m16;
  int rowA1 = rowA0 + 128;
  if (rowA0 >= M_TOT) rowA0 = M_TOT - 1;
  if (rowA1 >= M_TOT) rowA1 = M_TOT - 1;
  const unsigned short* pA0 = hmat + (size_t)rowA0 * H_DIM + g * 8;
  const unsigned short* pA1 = hmat + (size_t)rowA1 * H_DIM + g * 8;

  const int colB0 = nt * 256 + T0 * 16 + m16;
  const unsigned short* pB0 = w2t + (size_t)colB0 * H_DIM + g * 8;
  const unsigned short* pB1 = pB0 + (size_t)128 * H_DIM;

  const int wm = wave >> 1;
  const int wn = wave & 1;

  f32x4 acc[4][8] = {};

  {
    unsigned short* a = lsA + tid * 8;
    unsigned short* b = lsB + tid * 8;
    async16(pA0, a); async16(pA1, a + 4096);
    async16(pB0, b); async16(pB1, b + 4096);
    pA0 += 32; pA1 += 32; pB0 += 32; pB1 += 32;
  }

  int cbuf = 0;
  const int KT = H_DIM / 32;           // 64
  for (int kt = 0; kt < KT; ++kt) {
    __syncthreads();
    if (kt + 1 < KT) {
      unsigned short* a = lsA + (cbuf ^ 1) * 8192 + tid * 8;
      unsigned short* b = lsB + (cbuf ^ 1) * 8192 + tid * 8;
      async16(pA0, a); async16(pA1, a + 4096);
      async16(pB0, b); async16(pB1, b + 4096);
      pA0 += 32; pA1 += 32; pB0 += 32; pB1 += 32;
    }
    const bf16x8* lA = (const bf16x8*)(lsA + cbuf * 8192) + wm * 256 + lane;
    const bf16x8* lB = (const bf16x8*)(lsB + cbuf * 8192) + wn * 512 + lane;
    bf16x8 af[4], bfr[8];
#pragma unroll
    for (int t = 0; t < 4; ++t) af[t] = lA[t * 64];
#pragma unroll
    for (int u = 0; u < 8; ++u) bfr[u] = lB[u * 64];
#pragma unroll
    for (int t = 0; t < 4; ++t)
#pragma unroll
      for (int u = 0; u < 8; ++u)
        acc[t][u] = __builtin_amdgcn_mfma_f32_16x16x32_bf16(af[t], bfr[u], acc[t][u], 0, 0, 0);
    cbuf ^= 1;
  }

  const int ncol = nt * 256 + wn * 128 + (lane & 15);
  const int mrow = mt * 256 + wm * 64 + (lane >> 4) * 4;
#pragma unroll
  for (int u = 0; u < 8; ++u) {
    const int n = ncol + u * 16;
    const float bv = bias2[n];
#pragma unroll
    for (int t = 0; t < 4; ++t) {
#pragma unroll
      for (int r = 0; r < 4; ++r) {
        const int m = mrow + t * 16 + r;
        if (m < M_TOT) {
          const int b = m / L_DIM;
          const int l = m - b * L_DIM;
          out[(size_t)b * SXF + (size_t)l * F_DIM + n] = acc[t][u][r] + bv;
        }
      }
    }
  }
}

// ---------------- conversion / transpose / pad helpers ----------------------
__global__ void cvt_bf16_kernel(const float* __restrict__ in,
                                unsigned short* __restrict__ out, int n4) {
  int idx = blockIdx.x * 256 + threadIdx.x;
  if (idx < n4) {
    float4 v = ((const float4*)in)[idx];
    ushort4 o;
    o.x = f2bf(v.x); o.y = f2bf(v.y); o.z = f2bf(v.z); o.w = f2bf(v.w);
    ((ushort4*)out)[idx] = o;
  }
}

// out[c][r] = bf16(in[r][c]); R, C multiples of 64
__global__ void transpose_cvt_kernel(const float* __restrict__ in,
                                     unsigned short* __restrict__ out, int R, int C) {
  __shared__ unsigned short tile[64][72];
  const int tx = threadIdx.x & 15;
  const int ty = threadIdx.x >> 4;
  const int r0 = blockIdx.x * 64;
  const int c0 = blockIdx.y * 64;
#pragma unroll
  for (int i = 0; i < 4; ++i) {
    const int r = r0 + ty + i * 16;
    float4 v = *(const float4*)(in + (size_t)r * C + c0 + tx * 4);
    tile[ty + i * 16][tx * 4 + 0] = f2bf(v.x);
    tile[ty + i * 16][tx * 4 + 1] = f2bf(v.y);
    tile[ty + i * 16][tx * 4 + 2] = f2bf(v.z);
    tile[ty + i * 16][tx * 4 + 3] = f2bf(v.w);
  }
  __syncthreads();
#pragma unroll
  for (int i = 0; i < 4; ++i) {
    const int c = c0 + ty + i * 16;
    ushort4 o;
    o.x = tile[tx * 4 + 0][ty + i * 16];
    o.y = tile[tx * 4 + 1][ty + i * 16];
    o.z = tile[tx * 4 + 2][ty + i * 16];
    o.w = tile[tx * 4 + 3][ty + i * 16];
    *(ushort4*)(out + (size_t)c * R + r0 + tx * 4) = o;
  }
}

__global__ void zero_pad_kernel(float* __restrict__ out) {
  int idx = blockIdx.x * 256 + threadIdx.x;          // 8 * 15 * 128 float4s
  if (idx < B_DIM * 15 * 128) {
    int b = idx / (15 * 128);
    int rem = idx - b * (15 * 128);
    int l = L_DIM + rem / 128;
    int f4 = rem - (rem / 128) * 128;
    ((float4*)out)[(size_t)b * (SXF / 4) + (size_t)l * 128 + f4] =
        make_float4(0.f, 0.f, 0.f, 0.f);
  }
}

__global__ void fill_sentinel(float* out, int n) {   // distinctive ws-too-small marker
  int idx = blockIdx.x * 256 + threadIdx.x;
  if (idx < n) out[idx] = 12345.0f;
}

extern "C" void kernel_launch(void* const* d_in, const int* in_sizes, int n_in,
                              void* d_out, int out_size, void* d_ws, size_t ws_size,
                              hipStream_t stream) {
  const float* x  = (const float*)d_in[0];
  const float* w1 = (const float*)d_in[1];
  const float* b1 = (const float*)d_in[2];
  const float* w2 = (const float*)d_in[3];
  const float* b2 = (const float*)d_in[4];
  float* out = (float*)d_out;

  const size_t OFF_H   = 0;                               // 32648*2048*2 = 133726208
  const size_t OFF_XB  = 133726208;                       // 16777216*2   = 33554432
  const size_t OFF_W1T = OFF_XB + 33554432;               // 8192*2048*2  = 33554432
  const size_t OFF_W2T = OFF_W1T + 33554432;              // 2048*512*2   = 2097152
  const size_t WS_NEED = OFF_W2T + 2097152;               // ~202.9 MB

  if (ws_size < WS_NEED) {
    fill_sentinel<<<65536, 256, 0, stream>>>(out, out_size);
    return;
  }

  unsigned short* hbuf = (unsigned short*)((char*)d_ws + OFF_H);
  unsigned short* xb   = (unsigned short*)((char*)d_ws + OFF_XB);
  unsigned short* w1t  = (unsigned short*)((char*)d_ws + OFF_W1T);
  unsigned short* w2t  = (unsigned short*)((char*)d_ws + OFF_W2T);

  cvt_bf16_kernel<<<16384, 256, 0, stream>>>(x, xb, 4194304);
  transpose_cvt_kernel<<<dim3(128, 32), 256, 0, stream>>>(w1, w1t, 8192, 2048);
  transpose_cvt_kernel<<<dim3(32, 8), 256, 0, stream>>>(w2, w2t, 2048, 512);
  gemm1_kernel<<<1024, 512, 0, stream>>>(xb, w1t, b1, hbuf);
  gemm2_kernel<<<256, 512, 0, stream>>>(hbuf, w2t, b2, out);
  zero_pad_kernel<<<60, 256, 0, stream>>>(out);
}